// Round 16
// baseline (269.374 us; speedup 1.0000x reference)
//
#include <hip/hip_runtime.h>
#include <hip/hip_bf16.h>

#define B_ 4096
#define D_ 1024
#define H_ 8192
#define O_ 1000
#define K2 1024          // packed K: hi(xh/wh) only
#define NT 16            // K-tiles: 1024 / 64
#define NITER 8

typedef __attribute__((ext_vector_type(8))) short short8;
typedef __attribute__((ext_vector_type(4))) short short4v;
typedef __attribute__((ext_vector_type(4))) float f32x4;

union BF4 { __hip_bfloat16 b[4]; short4v s; };

__device__ __forceinline__ void gload16(void* ldsp, const void* g) {
  __builtin_amdgcn_global_load_lds(
      (const __attribute__((address_space(1))) unsigned int*)g,
      (__attribute__((address_space(3))) unsigned int*)ldsp, 16, 0, 0);
}

// ---- split: fp32 -> bf16 hi + full fp32 sum-of-squares + max ||w||^2 ----
__global__ __launch_bounds__(256) void split_all_kernel(
    const float* __restrict__ x, const float* __restrict__ w,
    __hip_bfloat16* __restrict__ Ap, __hip_bfloat16* __restrict__ Bp,
    float* __restrict__ xsq, float* __restrict__ wsq,
    unsigned* __restrict__ maxws)
{
  const int r = blockIdx.x;
  const int t = threadIdx.x;
  const float* src;
  __hip_bfloat16* dst;
  float* sq;
  const bool isW = (r >= B_);
  if (!isW) {
    src = x + (size_t)r * D_; dst = Ap + (size_t)r * K2; sq = xsq + r;
  } else {
    const int rr = r - B_;
    src = w + (size_t)rr * D_; dst = Bp + (size_t)rr * K2; sq = wsq + rr;
  }
  const float4 v = ((const float4*)src)[t];
  float ss = v.x * v.x + v.y * v.y + v.z * v.z + v.w * v.w;

  BF4 Hh;
  const float e[4] = {v.x, v.y, v.z, v.w};
#pragma unroll
  for (int i = 0; i < 4; ++i) Hh.b[i] = __float2bfloat16(e[i]);
  *(short4v*)(dst + t * 4) = Hh.s;

#pragma unroll
  for (int o = 32; o > 0; o >>= 1) ss += __shfl_down(ss, o);
  __shared__ float wsum[4];
  if ((t & 63) == 0) wsum[t >> 6] = ss;
  __syncthreads();
  if (t == 0) {
    const float tot = (wsum[0] + wsum[1]) + (wsum[2] + wsum[3]);
    *sq = tot;
    if (isW) atomicMax(maxws, __float_as_uint(tot));  // tot > 0
  }
}

// ---- 256x256 hi-GEMM (r8 structure: asm ds_read + counted lgkm/vmcnt) ----
// LDS dbuf d: A0@d+0, A1@d+16K, B0@d+32K, B1@d+48K; 128B rows; phys 16B-unit
// = logical ^ (row&7) via pre-swizzled global source (conflicts=0, r7/r8).
// Phase(mh,kk): 16 MFMA on regs read LAST phase; 8 asm ds_reads for NEXT.
// Gates: ph1 vmcnt(4), ph3 vmcnt(2); barriers only at gates (2/tile).
// Epilogue: dump u8 fixed-point residual scores r~ = wsq - 2*acc via LDS.

#define BAR() do { asm volatile("" ::: "memory"); \
                   __builtin_amdgcn_s_barrier(); \
                   asm volatile("" ::: "memory"); } while (0)
#define SB0() __builtin_amdgcn_sched_barrier(0)
#define GATE_S(S) asm volatile("s_waitcnt vmcnt(" S ")" ::: "memory")
#define LGKM8() do { asm volatile("s_waitcnt lgkmcnt(8)"); SB0(); } while (0)
#define LGKM0() do { asm volatile("s_waitcnt lgkmcnt(0)"); SB0(); } while (0)

#define DSR(dst, base, OFF) \
  asm volatile("ds_read_b128 %0, %1 offset:" OFF : "=v"(dst) : "v"(base))

#define RD4A(arr, base) do { unsigned _ba = (base); \
  DSR(arr[0], _ba, "0");    DSR(arr[1], _ba, "2048"); \
  DSR(arr[2], _ba, "4096"); DSR(arr[3], _ba, "6144"); } while (0)
#define RD4B(arr, base) do { unsigned _bb = (base); \
  DSR(arr[0], _bb, "0");     DSR(arr[1], _bb, "2048"); \
  DSR(arr[2], _bb, "16384"); DSR(arr[3], _bb, "18432"); } while (0)

#define STAGE(P, prow, T, isB, h) do { if ((T) < NT) { \
    const int koff_ = (T) * 64; \
    const __hip_bfloat16* s_ = (P) + (size_t)((prow) + (h)*128 + wid*16 + srow) * K2 + koff_ + sunit * 8; \
    char* d_ = lds + ((T)&1)*65536 + (isB)*32768 + (h)*16384 + wid*2048 + lane*16; \
    gload16(d_, s_); gload16(d_ + 1024, s_ + 8*K2); } } while (0)

#define MMQ(mh, A, B) do { \
    __builtin_amdgcn_s_setprio(1); \
    _Pragma("unroll") for (int m_ = 0; m_ < 4; ++m_) \
    _Pragma("unroll") for (int n_ = 0; n_ < 4; ++n_) \
      acc[(mh)*4+m_][n_] = __builtin_amdgcn_mfma_f32_16x16x32_bf16( \
          A[m_], B[n_], acc[(mh)*4+m_][n_], 0, 0, 0); \
    __builtin_amdgcn_s_setprio(0); \
    SB0(); } while (0)

#define TILE4(DS, TT, G1, RDN) do { \
    RD4A(s1A, aB01 + (DS)); \
    RD4B(s1B, bB1  + (DS)); \
    STAGE(Bp, bcol, (TT) + 1, 1, 1); \
    LGKM8(); \
    MMQ(0, s0A, s0B); \
    GATE_S(G1); BAR(); \
    RD4A(s0A, aB10 + (DS)); \
    RD4B(s0B, bB0  + (DS)); \
    STAGE(Ap, brow, (TT) + 1, 0, 0); \
    LGKM8(); \
    MMQ(0, s1A, s1B); \
    RD4A(s1A, aB11 + (DS)); \
    RD4B(s1B, bB1  + (DS)); \
    STAGE(Ap, brow, (TT) + 1, 0, 1); \
    LGKM8(); \
    MMQ(1, s0A, s0B); \
    GATE_S("2"); BAR(); \
    if (RDN) { \
      RD4A(s0A, aB00 + ((DS) ^ 65536)); \
      RD4B(s0B, bB0  + ((DS) ^ 65536)); \
      LGKM8(); \
    } else { LGKM0(); } \
    STAGE(Bp, bcol, (TT) + 2, 1, 0); \
    MMQ(1, s1A, s1B); \
  } while (0)

__global__ __launch_bounds__(512, 2) void gemm_hi_kernel(
    const __hip_bfloat16* __restrict__ Ap, const __hip_bfloat16* __restrict__ Bp,
    const float* __restrict__ wsq, unsigned char* __restrict__ scores)
{
  __shared__ char lds[131072];

  const int t = threadIdx.x;
  // XCD-aware: square 8x8 tile-chunk per XCD (r4-proven).
  const int id = blockIdx.x;
  const int xcd = id & 7;
  const int r_ = id >> 3;
  const int by = (xcd >> 2) * 8 + (r_ >> 3);
  const int bx = (xcd & 3) * 8 + (r_ & 7);
  const int brow = by * 256, bcol = bx * 256;

  const int lane = t & 63, wid = t >> 6;
  const int wm = wid >> 2, wn = wid & 3;
  const int cc = lane & 15, q = lane >> 4, sw = lane & 7;
  const int kof0 = (q ^ sw) * 16;
  const int kof1 = ((4 + q) ^ sw) * 16;

  const int srow = lane >> 3;
  const int sunit = (lane & 7) ^ srow;

  const unsigned lb = (unsigned)(uintptr_t)lds;
  const unsigned aRow = (unsigned)((wm * 64 + cc) * 128);
  const unsigned bRow = (unsigned)(32768 + (wn * 32 + cc) * 128);
  const unsigned aB00 = lb + aRow + kof0;
  const unsigned aB01 = lb + aRow + kof1;
  const unsigned aB10 = lb + 16384 + aRow + kof0;
  const unsigned aB11 = lb + 16384 + aRow + kof1;
  const unsigned bB0 = lb + bRow + kof0;
  const unsigned bB1 = lb + bRow + kof1;

  f32x4 acc[8][4] = {};
  short8 s0A[4], s0B[4], s1A[4], s1B[4];

  // Prologue (FIFO: T0.B0 T0.B1 T0.A0 T0.A1 T1.B0); gate leaves {T0.A1,T1.B0}
  STAGE(Bp, bcol, 0, 1, 0);
  STAGE(Bp, bcol, 0, 1, 1);
  STAGE(Ap, brow, 0, 0, 0);
  STAGE(Ap, brow, 0, 0, 1);
  STAGE(Bp, bcol, 1, 1, 0);
  GATE_S("4");
  BAR();
  RD4A(s0A, aB00);
  RD4B(s0B, bB0);
  SB0();

  for (int it = 0; it < NITER - 1; ++it) {
    const int a = 2 * it;
    TILE4(0,     a,     "4", 1);
    TILE4(65536, a + 1, "4", 1);
  }
  TILE4(0,     NT - 2, "4", 1);
  TILE4(65536, NT - 1, "0", 0);

  // ---- dump epilogue: u8 scores q = clamp((r~ + 16)*8 + .5), r~ = wsq-2acc
  BAR();   // all waves done reading LDS before reuse
  unsigned char* sb = (unsigned char*)lds;
#pragma unroll
  for (int i = 0; i < 8; ++i) {
    const int mh = i >> 2, m_ = i & 3;
#pragma unroll
    for (int rr = 0; rr < 4; ++rr) {
      const int row = mh * 128 + wm * 64 + m_ * 16 + q * 4 + rr;
#pragma unroll
      for (int j = 0; j < 4; ++j) {
        const int col = (j >> 1) * 128 + wn * 32 + (j & 1) * 16 + cc;
        const float rv = wsq[bcol + col] - 2.0f * acc[i][j][rr];
        int qv = (int)(rv * 8.0f + 128.5f);
        qv = qv < 0 ? 0 : (qv > 255 ? 255 : qv);
        sb[row * 256 + col] = (unsigned char)qv;
      }
    }
  }
  BAR();
  {
    unsigned char* gs = scores + (size_t)brow * H_ + bcol;
#pragma unroll
    for (int itr = 0; itr < 8; ++itr) {
      const int row = wid * 32 + itr * 4 + (lane >> 4);
      const int bo = (lane & 15) * 16;
      *(float4*)(gs + (size_t)row * H_ + bo) = *(const float4*)(sb + row * 256 + bo);
    }
  }
}

// ---- transpose G [O,H] -> GT [H,O] ----
__global__ __launch_bounds__(256) void transposeG_kernel(
    const float* __restrict__ G, float* __restrict__ GT)
{
  __shared__ float tile[32][33];
  const int h0 = blockIdx.x * 32;
  const int o0 = blockIdx.y * 32;
  const int tx = threadIdx.x;
  const int ty = threadIdx.y;
#pragma unroll
  for (int j = 0; j < 4; ++j) {
    const int o = o0 + ty + j * 8;
    if (o < O_) tile[ty + j * 8][tx] = G[(size_t)o * H_ + h0 + tx];
  }
  __syncthreads();
  const int o = o0 + tx;
  if (o < O_) {
#pragma unroll
    for (int j = 0; j < 4; ++j)
      GT[(size_t)(h0 + ty + j * 8) * O_ + o] = tile[tx][ty + j * 8];
  }
}

// ---- scan + rescue (numpy fp32-rounding-chain semantics) + gather ----
// Window (unchanged, r15): |s~ - s'| <= 2*2^-8*||x||*||w|| + accum noise;
// both endpoints + 2.5x margin => Wr = 0.040*||x||*Wmax + 0.05, +3 buckets.
// FIX vs r15: the final comparison replicates numpy exactly:
//   m  = fp32(dot)            (fp64 dot rounded; ~=numpy's fp32 BLAS accum)
//   a  = fp32(x_sq - 2*m); s = fp32(a + w_sq)   <- x_sq~1024 grid-quantizes
//   argmin with tie -> smallest h  (numpy first-occurrence)
// r15 compared exact fp64 scores without x_sq: grid ties resolved wrongly.
__global__ __launch_bounds__(256) void scan_rescue_kernel(
    const unsigned char* __restrict__ scores,
    const float* __restrict__ x, const float* __restrict__ w,
    const float* __restrict__ xsq, const float* __restrict__ wsq,
    const unsigned* __restrict__ maxws,
    const float* __restrict__ GT, float* __restrict__ out)
{
  const int b = blockIdx.x, t = threadIdx.x;
  const int lane = t & 63, wv = t >> 6;
  __shared__ float xl_[D_];
  __shared__ unsigned wmin[4];
  __shared__ int cnt;
  __shared__ short cand[512];
  __shared__ float bs_[4];
  __shared__ int bh_[4];

  union { uint4 v[2]; unsigned char c[32]; } u;
  const uint4* sv = (const uint4*)(scores + (size_t)b * H_);
  u.v[0] = sv[2 * t];
  u.v[1] = sv[2 * t + 1];

  ((float4*)xl_)[t] = ((const float4*)(x + (size_t)b * D_))[t];
  if (t == 0) cnt = 0;

  unsigned m = 255;
#pragma unroll
  for (int i = 0; i < 32; ++i) m = min(m, (unsigned)u.c[i]);
#pragma unroll
  for (int o = 32; o > 0; o >>= 1)
    m = min(m, (unsigned)__shfl_xor((int)m, o));
  if (lane == 0) wmin[wv] = m;
  __syncthreads();
  m = min(min(wmin[0], wmin[1]), min(wmin[2], wmin[3]));

  const float Wmax = sqrtf(__uint_as_float(*maxws));
  const float xsb = xsq[b];
  const float Wr = 0.040f * sqrtf(xsb) * Wmax + 0.05f;
  const unsigned Tq = m + (unsigned)(Wr * 8.0f) + 3;

#pragma unroll
  for (int i = 0; i < 32; ++i)
    if ((unsigned)u.c[i] <= Tq) {
      const int p = atomicAdd(&cnt, 1);
      if (p < 512) cand[p] = (short)(t * 32 + i);
    }
  __syncthreads();
  const int n = min(cnt, 512);

  // wave wv handles candidates c = wv, wv+4, ... (intra-wave reduce only)
  float bestv = 3.4e38f;
  int besth = H_;
  for (int c = wv; c < n; c += 4) {
    const int h = (int)cand[c];
    const float* wr = w + (size_t)h * D_;
    double p = 0.0;
#pragma unroll
    for (int seg = 0; seg < 4; ++seg) {
      const int o4 = seg * 256 + lane * 4;
      const float4 xv = *(const float4*)(xl_ + o4);
      const float4 wq = *(const float4*)(wr + o4);
      p += (double)xv.x * wq.x + (double)xv.y * wq.y +
           (double)xv.z * wq.z + (double)xv.w * wq.w;
    }
#pragma unroll
    for (int o = 32; o > 0; o >>= 1) p += __shfl_down(p, o);
    if (lane == 0) {
      const float mf = (float)p;
      const float a = xsb - 2.0f * mf;   // numpy fp32 chain
      const float s = a + wsq[h];
      if (s < bestv || (s == bestv && h < besth)) { bestv = s; besth = h; }
    }
  }
  if (lane == 0) { bs_[wv] = bestv; bh_[wv] = besth; }
  __syncthreads();
  if (t == 0) {
    float bv = bs_[0]; int bh = bh_[0];
#pragma unroll
    for (int i = 1; i < 4; ++i)
      if (bs_[i] < bv || (bs_[i] == bv && bh_[i] < bh)) { bv = bs_[i]; bh = bh_[i]; }
    bh_[0] = bh;
  }
  __syncthreads();
  const int fh = bh_[0];

  const float* g = GT + (size_t)fh * O_;
  float4* od = (float4*)(out + (size_t)b * O_);
  for (int i = t; i < O_ / 4; i += 256) od[i] = ((const float4*)g)[i];
  if (t == 0) out[(size_t)B_ * O_ + b] = (float)fh;
}

extern "C" void kernel_launch(void* const* d_in, const int* in_sizes, int n_in,
                              void* d_out, int out_size, void* d_ws, size_t ws_size,
                              hipStream_t stream)
{
  (void)in_sizes; (void)n_in; (void)out_size; (void)ws_size;
  const float* x = (const float*)d_in[0];
  const float* kw = (const float*)d_in[1];
  const float* gw = (const float*)d_in[2];
  float* out = (float*)d_out;

  char* ws = (char*)d_ws;
  // GT 32.8MB @0 | Ap 8.4MB | Bp 16.8MB | xsq | wsq | maxws | scores 32MB
  float* GT = (float*)(ws);
  __hip_bfloat16* Ap = (__hip_bfloat16*)(ws + 33554432);
  __hip_bfloat16* Bp = (__hip_bfloat16*)(ws + 41943040);
  float* xsq = (float*)(ws + 58720256);
  float* wsq = (float*)(ws + 58736640);
  unsigned* maxws = (unsigned*)(ws + 58769408);
  unsigned char* scores = (unsigned char*)(ws + 58785792);

  hipMemsetAsync(maxws, 0, 16, stream);
  split_all_kernel<<<B_ + H_, 256, 0, stream>>>(x, kw, Ap, Bp, xsq, wsq, maxws);
  gemm_hi_kernel<<<512, 512, 0, stream>>>(Ap, Bp, wsq, scores);
  transposeG_kernel<<<dim3(H_ / 32, (O_ + 31) / 32), dim3(32, 8), 0, stream>>>(gw, GT);
  scan_rescue_kernel<<<B_, 256, 0, stream>>>(scores, x, kw, xsq, wsq, maxws, GT, out);
}